// Round 1
// baseline (211.157 us; speedup 1.0000x reference)
//
#include <hip/hip_runtime.h>

#define B 256
#define M 8
#define L 64
#define E 128
#define H 8
#define HD 16
#define NET 8
#define E3 384

// ---------------------------------------------------------------------------
// K0: transpose Wqkv [384,128] -> WqkvT [128,384]; Wo [128,128] -> WoT [128,128]
// so that GEMM inner loops read weights coalesced over the output dim.
// ---------------------------------------------------------------------------
__global__ __launch_bounds__(256) void k_transpose(
    const float* __restrict__ Wqkv, const float* __restrict__ Wo,
    float* __restrict__ WqkvT, float* __restrict__ WoT) {
  int idx = blockIdx.x * 256 + threadIdx.x;   // grid covers exactly 65536
  if (idx < E * E3) {
    int e = idx / E3;
    int o = idx - e * E3;
    WqkvT[idx] = Wqkv[o * E + e];
  } else {
    int j = idx - E * E3;                     // j < 16384 by construction
    int e = j >> 7, o = j & 127;
    WoT[j] = Wo[o * E + e];
  }
}

// ---------------------------------------------------------------------------
// K1: gather + elementwise fuse + mean over walk.  One block per (b,m).
// 256 threads = 8 step-groups x 32 lanes; lane owns a float4 (16B) of E.
// agg0[b*M+m][e] = (1/64) * sum_l (NT[n1]+fb)*(NT[n2]+fb)*ET[et]
// ---------------------------------------------------------------------------
__global__ __launch_bounds__(256) void k_gather(
    const int* __restrict__ walks, const float* __restrict__ node_table,
    const float* __restrict__ fc1_b, const float* __restrict__ edge_table,
    float* __restrict__ agg0) {
  __shared__ int s_idx[L * 3];
  __shared__ float s_et[NET * E];
  __shared__ float4 s_red[256];

  int r = blockIdx.x;              // b*M + m
  int t = threadIdx.x;
  int g = t >> 5, lane = t & 31;

  if (t < L * 3) s_idx[t] = walks[r * (L * 3) + t];
  for (int i = t; i < NET * E; i += 256) s_et[i] = edge_table[i];
  __syncthreads();

  const float4* nt4 = (const float4*)node_table;   // row stride = 32 float4
  float4 fb = ((const float4*)fc1_b)[lane];
  float4 acc = make_float4(0.f, 0.f, 0.f, 0.f);

  #pragma unroll
  for (int i = 0; i < 8; ++i) {
    int l = (i << 3) + g;
    int n1 = s_idx[3 * l];
    int n2 = s_idx[3 * l + 1];
    int et = s_idx[3 * l + 2];
    float4 a = nt4[n1 * 32 + lane];
    float4 c = nt4[n2 * 32 + lane];
    float4 ev = ((const float4*)(s_et + et * E))[lane];
    acc.x += (a.x + fb.x) * (c.x + fb.x) * ev.x;
    acc.y += (a.y + fb.y) * (c.y + fb.y) * ev.y;
    acc.z += (a.z + fb.z) * (c.z + fb.z) * ev.z;
    acc.w += (a.w + fb.w) * (c.w + fb.w) * ev.w;
  }
  s_red[t] = acc;
  __syncthreads();
  if (t < 32) {
    float4 s = s_red[t];
    #pragma unroll
    for (int gg = 1; gg < 8; ++gg) {
      float4 v = s_red[gg * 32 + t];
      s.x += v.x; s.y += v.y; s.z += v.z; s.w += v.w;
    }
    const float inv = 1.0f / (float)L;
    s.x *= inv; s.y *= inv; s.z *= inv; s.w *= inv;
    ((float4*)agg0)[r * 32 + t] = s;
  }
}

// ---------------------------------------------------------------------------
// K2: per-metapath indexed linear.  agg1[b,m,o] = sum_e agg0[b,m,e]*W[mp,e,o] + b[mp,o]
// Block = (m, 8 b-rows); 128 threads, thread t = output col o.  W reads coalesced.
// ---------------------------------------------------------------------------
__global__ __launch_bounds__(128) void k_mplinear(
    const float* __restrict__ agg0, const int* __restrict__ mp_type_idx,
    const float* __restrict__ W_mp, const float* __restrict__ b_mp,
    float* __restrict__ agg1) {
  __shared__ float xs[8][E];
  int t = threadIdx.x;
  int m = blockIdx.y;
  int b0 = blockIdx.x * 8;
  int mp = mp_type_idx[m];
  #pragma unroll
  for (int j = 0; j < 8; ++j)
    xs[j][t] = agg0[((b0 + j) * M + m) * E + t];
  __syncthreads();
  float acc[8] = {0, 0, 0, 0, 0, 0, 0, 0};
  const float* W = W_mp + mp * E * E;
  for (int e = 0; e < E; ++e) {
    float w = W[e * E + t];
    #pragma unroll
    for (int j = 0; j < 8; ++j) acc[j] += xs[j][e] * w;
  }
  float bias = b_mp[mp * E + t];
  #pragma unroll
  for (int j = 0; j < 8; ++j)
    agg1[((b0 + j) * M + m) * E + t] = acc[j] + bias;
}

// ---------------------------------------------------------------------------
// K3: qkv = agg1 @ WqkvT + bqkv.  Tokens flat r = b*M+m (weights shared).
// Block = (8 token rows, one of 3 output chunks of 128); thread t = col.
// ---------------------------------------------------------------------------
__global__ __launch_bounds__(128) void k_qkv(
    const float* __restrict__ agg1, const float* __restrict__ WqkvT,
    const float* __restrict__ bqkv, float* __restrict__ qkv) {
  __shared__ float xs[8][E];
  int t = threadIdx.x;
  int r0 = blockIdx.x * 8;
  int o = blockIdx.y * E + t;
  #pragma unroll
  for (int j = 0; j < 8; ++j)
    xs[j][t] = agg1[(r0 + j) * E + t];
  __syncthreads();
  float acc[8] = {0, 0, 0, 0, 0, 0, 0, 0};
  for (int e = 0; e < E; ++e) {
    float w = WqkvT[e * E3 + o];
    #pragma unroll
    for (int j = 0; j < 8; ++j) acc[j] += xs[j][e] * w;
  }
  float bias = bqkv[o];
  #pragma unroll
  for (int j = 0; j < 8; ++j)
    qkv[(r0 + j) * E3 + o] = acc[j] + bias;
}

// ---------------------------------------------------------------------------
// K4: attention over M=8 metapaths (per b) + output projection.
// Block per b, 256 threads.  All intermediates in LDS.
// out[(m*B+b)*E + o] = (softmax(QK^T/4) V)[m] @ Wo^T + bo
// ---------------------------------------------------------------------------
__global__ __launch_bounds__(256) void k_attn(
    const float* __restrict__ qkv, const float* __restrict__ WoT,
    const float* __restrict__ bo, float* __restrict__ out) {
  __shared__ float s_qkv[M][E3 + 1];     // +1 pad: row stride 385 breaks bank alias
  __shared__ float s_sc[H][M][M];
  __shared__ float s_o[M][E];
  int b = blockIdx.x;
  int t = threadIdx.x;

  #pragma unroll
  for (int i = 0; i < 12; ++i) {
    int idx = i * 256 + t;               // 0..3071
    int mt = idx / E3;
    int col = idx - mt * E3;
    s_qkv[mt][col] = qkv[(b * M + mt) * E3 + col];
  }
  __syncthreads();

  // scores[h][m][n] = q_m,h . k_n,h / sqrt(16)
  #pragma unroll
  for (int i = 0; i < 2; ++i) {
    int idx = i * 256 + t;               // 0..511
    int h = idx >> 6;
    int mq = (idx >> 3) & 7;
    int n = idx & 7;
    float s = 0.f;
    #pragma unroll
    for (int d = 0; d < HD; ++d)
      s += s_qkv[mq][h * HD + d] * s_qkv[n][E + h * HD + d];
    s_sc[h][mq][n] = s * 0.25f;
  }
  __syncthreads();

  // softmax over n (8 values) — one thread per (h,m) row
  if (t < 64) {
    int h = t >> 3, mq = t & 7;
    float mx = -1e30f;
    #pragma unroll
    for (int n = 0; n < 8; ++n) mx = fmaxf(mx, s_sc[h][mq][n]);
    float ex[8];
    float sum = 0.f;
    #pragma unroll
    for (int n = 0; n < 8; ++n) { ex[n] = __expf(s_sc[h][mq][n] - mx); sum += ex[n]; }
    float inv = 1.0f / sum;
    #pragma unroll
    for (int n = 0; n < 8; ++n) s_sc[h][mq][n] = ex[n] * inv;
  }
  __syncthreads();

  // o[m][h*16+d] = sum_n attn[h][m][n] * v[n][h*16+d]
  #pragma unroll
  for (int i = 0; i < 4; ++i) {
    int idx = i * 256 + t;               // 0..1023
    int mq = idx >> 7;
    int col = idx & 127;
    int h = col >> 4;
    float s = 0.f;
    #pragma unroll
    for (int n = 0; n < 8; ++n)
      s += s_sc[h][mq][n] * s_qkv[n][2 * E + col];
    s_o[mq][col] = s;
  }
  __syncthreads();

  // out proj: thread owns col o for 4 m-values (m = 2*i + t/128)
  int o = t & 127;
  int mbase = t >> 7;
  float accp[4] = {0, 0, 0, 0};
  for (int e = 0; e < E; ++e) {
    float w = WoT[e * E + o];
    #pragma unroll
    for (int i = 0; i < 4; ++i)
      accp[i] += s_o[2 * i + mbase][e] * w;
  }
  float bias = bo[o];
  #pragma unroll
  for (int i = 0; i < 4; ++i) {
    int mq = 2 * i + mbase;
    out[(mq * B + b) * E + o] = accp[i] + bias;
  }
}

// ---------------------------------------------------------------------------
extern "C" void kernel_launch(void* const* d_in, const int* in_sizes, int n_in,
                              void* d_out, int out_size, void* d_ws, size_t ws_size,
                              hipStream_t stream) {
  // setup_inputs order:
  // 0 node_idx (unused), 1 mp_type_idx, 2 node_mp_walks, 3 node_table, 4 fc1_b,
  // 5 edge_table, 6 W_mp, 7 b_mp, 8 Wqkv, 9 bqkv, 10 Wo, 11 bo
  const int*   mp_type_idx = (const int*)d_in[1];
  const int*   walks       = (const int*)d_in[2];
  const float* node_table  = (const float*)d_in[3];
  const float* fc1_b       = (const float*)d_in[4];
  const float* edge_table  = (const float*)d_in[5];
  const float* W_mp        = (const float*)d_in[6];
  const float* b_mp        = (const float*)d_in[7];
  const float* Wqkv        = (const float*)d_in[8];
  const float* bqkv        = (const float*)d_in[9];
  const float* Wo          = (const float*)d_in[10];
  const float* bo          = (const float*)d_in[11];
  float* out = (float*)d_out;

  char* ws = (char*)d_ws;
  float* agg0  = (float*)(ws);                               // 1 MB
  float* agg1  = (float*)(ws + (1 << 20));                   // 1 MB
  float* qkvb  = (float*)(ws + (2 << 20));                   // 3 MB
  float* WqkvT = (float*)(ws + (5 << 20));                   // 192 KB
  float* WoT   = (float*)(ws + (5 << 20) + (256 << 10));     // 64 KB

  k_transpose<<<dim3(256), dim3(256), 0, stream>>>(Wqkv, Wo, WqkvT, WoT);
  k_gather<<<dim3(B * M), dim3(256), 0, stream>>>(walks, node_table, fc1_b, edge_table, agg0);
  k_mplinear<<<dim3(32, 8), dim3(128), 0, stream>>>(agg0, mp_type_idx, W_mp, b_mp, agg1);
  k_qkv<<<dim3(256, 3), dim3(128), 0, stream>>>(agg1, WqkvT, bqkv, qkvb);
  k_attn<<<dim3(B), dim3(256), 0, stream>>>(qkvb, WoT, bo, out);
}

// Round 2
// 208.228 us; speedup vs baseline: 1.0141x; 1.0141x over previous
//
#include <hip/hip_runtime.h>

#define B 256
#define M 8
#define L 64
#define E 128
#define H 8
#define HD 16
#define NET 8
#define E3 384

// ---------------------------------------------------------------------------
// K0: transpose Wqkv [384,128] -> WqkvT [128,384]; Wo [128,128] -> WoT [128,128]
// ---------------------------------------------------------------------------
__global__ __launch_bounds__(256) void k_transpose(
    const float* __restrict__ Wqkv, const float* __restrict__ Wo,
    float* __restrict__ WqkvT, float* __restrict__ WoT) {
  int idx = blockIdx.x * 256 + threadIdx.x;   // grid covers exactly 65536
  if (idx < E * E3) {
    int e = idx / E3;
    int o = idx - e * E3;
    WqkvT[idx] = Wqkv[o * E + e];
  } else {
    int j = idx - E * E3;                     // j < 16384
    int e = j >> 7, o = j & 127;
    WoT[j] = Wo[o * E + e];
  }
}

// ---------------------------------------------------------------------------
// K1: gather + elementwise fuse + mean over walk.  One block per (b,m).
// 256 threads = 8 step-groups x 32 lanes; lane owns a float4 (16B) of E.
// ---------------------------------------------------------------------------
__global__ __launch_bounds__(256) void k_gather(
    const int* __restrict__ walks, const float* __restrict__ node_table,
    const float* __restrict__ fc1_b, const float* __restrict__ edge_table,
    float* __restrict__ agg0) {
  __shared__ int s_idx[L * 3];
  __shared__ float s_et[NET * E];
  __shared__ float4 s_red[256];

  int r = blockIdx.x;              // b*M + m
  int t = threadIdx.x;
  int g = t >> 5, lane = t & 31;

  if (t < L * 3) s_idx[t] = walks[r * (L * 3) + t];
  for (int i = t; i < NET * E; i += 256) s_et[i] = edge_table[i];
  __syncthreads();

  const float4* nt4 = (const float4*)node_table;   // row stride = 32 float4
  float4 fb = ((const float4*)fc1_b)[lane];
  float4 acc = make_float4(0.f, 0.f, 0.f, 0.f);

  #pragma unroll
  for (int i = 0; i < 8; ++i) {
    int l = (i << 3) + g;
    int n1 = s_idx[3 * l];
    int n2 = s_idx[3 * l + 1];
    int et = s_idx[3 * l + 2];
    float4 a = nt4[n1 * 32 + lane];
    float4 c = nt4[n2 * 32 + lane];
    float4 ev = ((const float4*)(s_et + et * E))[lane];
    acc.x += (a.x + fb.x) * (c.x + fb.x) * ev.x;
    acc.y += (a.y + fb.y) * (c.y + fb.y) * ev.y;
    acc.z += (a.z + fb.z) * (c.z + fb.z) * ev.z;
    acc.w += (a.w + fb.w) * (c.w + fb.w) * ev.w;
  }
  s_red[t] = acc;
  __syncthreads();
  if (t < 32) {
    float4 s = s_red[t];
    #pragma unroll
    for (int gg = 1; gg < 8; ++gg) {
      float4 v = s_red[gg * 32 + t];
      s.x += v.x; s.y += v.y; s.z += v.z; s.w += v.w;
    }
    const float inv = 1.0f / (float)L;
    s.x *= inv; s.y *= inv; s.z *= inv; s.w *= inv;
    ((float4*)agg0)[r * 32 + t] = s;
  }
}

// ---------------------------------------------------------------------------
// K2 (fused): per-metapath linear + QKV projection, agg1 kept in LDS.
// Block = (b-group of 8, m); 256 threads = (half: rows 0-3 / 4-7) x (o: 0..127).
// qkv[(b*M+m)*E3 + o] = (agg0 @ W_mp[mp] + b_mp[mp]) @ Wqkv^T + bqkv
// ---------------------------------------------------------------------------
__global__ __launch_bounds__(256) void k_mlp(
    const float* __restrict__ agg0, const int* __restrict__ mp_type_idx,
    const float* __restrict__ W_mp, const float* __restrict__ b_mp,
    const float* __restrict__ WqkvT, const float* __restrict__ bqkv,
    float* __restrict__ qkv) {
  __shared__ float xs[8][E];   // agg0 rows
  __shared__ float ys[8][E];   // agg1 rows
  int t = threadIdx.x;
  int m = blockIdx.y;
  int b0 = blockIdx.x * 8;
  int mp = mp_type_idx[m];
  int o = t & 127;
  int half = t >> 7;           // 0: rows 0-3, 1: rows 4-7

  #pragma unroll
  for (int i = 0; i < 4; ++i) {
    int idx = i * 256 + t;     // 0..1023
    int j = idx >> 7, e = idx & 127;
    xs[j][e] = agg0[((b0 + j) * M + m) * E + e];
  }
  __syncthreads();

  // phase 1: ys = xs @ W_mp[mp] + b_mp[mp]
  {
    const float* W = W_mp + mp * E * E;
    float acc[4] = {0, 0, 0, 0};
    for (int e = 0; e < E; ++e) {
      float w = W[e * E + o];
      #pragma unroll
      for (int j = 0; j < 4; ++j) acc[j] += xs[half * 4 + j][e] * w;
    }
    float bias = b_mp[mp * E + o];
    #pragma unroll
    for (int j = 0; j < 4; ++j) ys[half * 4 + j][o] = acc[j] + bias;
  }
  __syncthreads();

  // phase 2: qkv = ys @ WqkvT + bqkv   (3 chunks of 128 outputs)
  #pragma unroll
  for (int c = 0; c < 3; ++c) {
    int oc = c * E + o;
    float acc[4] = {0, 0, 0, 0};
    for (int e = 0; e < E; ++e) {
      float w = WqkvT[e * E3 + oc];
      #pragma unroll
      for (int j = 0; j < 4; ++j) acc[j] += ys[half * 4 + j][e] * w;
    }
    float bias = bqkv[oc];
    #pragma unroll
    for (int j = 0; j < 4; ++j)
      qkv[((b0 + half * 4 + j) * M + m) * E3 + oc] = acc[j] + bias;
  }
}

// ---------------------------------------------------------------------------
// K3: attention over M=8 metapaths (per b) + output projection.
// ---------------------------------------------------------------------------
__global__ __launch_bounds__(256) void k_attn(
    const float* __restrict__ qkv, const float* __restrict__ WoT,
    const float* __restrict__ bo, float* __restrict__ out) {
  __shared__ float s_qkv[M][E3 + 1];
  __shared__ float s_sc[H][M][M];
  __shared__ float s_o[M][E];
  int b = blockIdx.x;
  int t = threadIdx.x;

  #pragma unroll
  for (int i = 0; i < 12; ++i) {
    int idx = i * 256 + t;               // 0..3071
    int mt = idx / E3;
    int col = idx - mt * E3;
    s_qkv[mt][col] = qkv[(b * M + mt) * E3 + col];
  }
  __syncthreads();

  #pragma unroll
  for (int i = 0; i < 2; ++i) {
    int idx = i * 256 + t;               // 0..511
    int h = idx >> 6;
    int mq = (idx >> 3) & 7;
    int n = idx & 7;
    float s = 0.f;
    #pragma unroll
    for (int d = 0; d < HD; ++d)
      s += s_qkv[mq][h * HD + d] * s_qkv[n][E + h * HD + d];
    s_sc[h][mq][n] = s * 0.25f;
  }
  __syncthreads();

  if (t < 64) {
    int h = t >> 3, mq = t & 7;
    float mx = -1e30f;
    #pragma unroll
    for (int n = 0; n < 8; ++n) mx = fmaxf(mx, s_sc[h][mq][n]);
    float ex[8];
    float sum = 0.f;
    #pragma unroll
    for (int n = 0; n < 8; ++n) { ex[n] = __expf(s_sc[h][mq][n] - mx); sum += ex[n]; }
    float inv = 1.0f / sum;
    #pragma unroll
    for (int n = 0; n < 8; ++n) s_sc[h][mq][n] = ex[n] * inv;
  }
  __syncthreads();

  #pragma unroll
  for (int i = 0; i < 4; ++i) {
    int idx = i * 256 + t;               // 0..1023
    int mq = idx >> 7;
    int col = idx & 127;
    int h = col >> 4;
    float s = 0.f;
    #pragma unroll
    for (int n = 0; n < 8; ++n)
      s += s_sc[h][mq][n] * s_qkv[n][2 * E + col];
    s_o[mq][col] = s;
  }
  __syncthreads();

  int o = t & 127;
  int mbase = t >> 7;
  float accp[4] = {0, 0, 0, 0};
  for (int e = 0; e < E; ++e) {
    float w = WoT[e * E + o];
    #pragma unroll
    for (int i = 0; i < 4; ++i)
      accp[i] += s_o[2 * i + mbase][e] * w;
  }
  float bias = bo[o];
  #pragma unroll
  for (int i = 0; i < 4; ++i) {
    int mq = 2 * i + mbase;
    out[(mq * B + b) * E + o] = accp[i] + bias;
  }
}

// ---------------------------------------------------------------------------
extern "C" void kernel_launch(void* const* d_in, const int* in_sizes, int n_in,
                              void* d_out, int out_size, void* d_ws, size_t ws_size,
                              hipStream_t stream) {
  const int*   mp_type_idx = (const int*)d_in[1];
  const int*   walks       = (const int*)d_in[2];
  const float* node_table  = (const float*)d_in[3];
  const float* fc1_b       = (const float*)d_in[4];
  const float* edge_table  = (const float*)d_in[5];
  const float* W_mp        = (const float*)d_in[6];
  const float* b_mp        = (const float*)d_in[7];
  const float* Wqkv        = (const float*)d_in[8];
  const float* bqkv        = (const float*)d_in[9];
  const float* Wo          = (const float*)d_in[10];
  const float* bo          = (const float*)d_in[11];
  float* out = (float*)d_out;

  char* ws = (char*)d_ws;
  float* agg0  = (float*)(ws);                               // 1 MB
  float* qkvb  = (float*)(ws + (1 << 20));                   // 3 MB
  float* WqkvT = (float*)(ws + (4 << 20));                   // 192 KB
  float* WoT   = (float*)(ws + (4 << 20) + (256 << 10));     // 64 KB

  k_transpose<<<dim3(256), dim3(256), 0, stream>>>(Wqkv, Wo, WqkvT, WoT);
  k_gather<<<dim3(B * M), dim3(256), 0, stream>>>(walks, node_table, fc1_b, edge_table, agg0);
  k_mlp<<<dim3(32, 8), dim3(256), 0, stream>>>(agg0, mp_type_idx, W_mp, b_mp, WqkvT, bqkv, qkvb);
  k_attn<<<dim3(B), dim3(256), 0, stream>>>(qkvb, WoT, bo, out);
}

// Round 3
// 203.701 us; speedup vs baseline: 1.0366x; 1.0222x over previous
//
#include <hip/hip_runtime.h>

#define B 256
#define M 8
#define L 64
#define E 128
#define H 8
#define HD 16
#define NET 8
#define E3 384

// ---------------------------------------------------------------------------
// K0: transpose Wqkv [384,128] -> WqkvT [128,384]; Wo [128,128] -> WoT [128,128]
// so weight reads in the fused kernel are coalesced float4 over the output dim.
// ---------------------------------------------------------------------------
__global__ __launch_bounds__(256) void k_transpose(
    const float* __restrict__ Wqkv, const float* __restrict__ Wo,
    float* __restrict__ WqkvT, float* __restrict__ WoT) {
  int idx = blockIdx.x * 256 + threadIdx.x;   // grid covers exactly 65536
  if (idx < E * E3) {
    int e = idx / E3;
    int o = idx - e * E3;
    WqkvT[idx] = Wqkv[o * E + e];
  } else {
    int j = idx - E * E3;                     // j < 16384
    int e = j >> 7, o = j & 127;
    WoT[j] = Wo[o * E + e];
  }
}

// ---------------------------------------------------------------------------
// K1 (fully fused): one block per target node b.  256 threads = 8 groups x 32.
// Group g owns metapath m=g through every phase; all intermediates in LDS.
//   ph1: agg0[m] = mean_l (NT[n1]+fb)*(NT[n2]+fb)*ET[e]        (gather, HBM)
//   ph2: agg1[m] = agg0[m] @ W_mp[mp(m)] + b_mp[mp(m)]         (L2-resident W)
//   ph3: qkv[m]  = agg1[m] @ WqkvT + bqkv
//   ph4: scores/softmax/AV over M=8, heads=8
//   ph5: out[m*B+b] = o[m] @ WoT + bo
// ---------------------------------------------------------------------------
__global__ __launch_bounds__(256) void k_fused(
    const int* __restrict__ walks, const float* __restrict__ node_table,
    const float* __restrict__ fc1_b, const float* __restrict__ edge_table,
    const int* __restrict__ mp_type_idx,
    const float* __restrict__ W_mp, const float* __restrict__ b_mp,
    const float* __restrict__ WqkvT, const float* __restrict__ bqkv,
    const float* __restrict__ WoT, const float* __restrict__ bo,
    float* __restrict__ out) {
  __shared__ int   s_idx[M][L][3];        // 6 KB walk triples for this b
  __shared__ float s_et[NET * E];         // 4 KB edge table
  __shared__ float s_x[M][E];             // agg0
  __shared__ float s_y[M][E];             // agg1
  __shared__ float s_qkv[M][E3 + 1];      // +1 pad: rows land on distinct banks
  __shared__ float s_sc[H][M][M];
  __shared__ float s_o[M][E];
  __shared__ int   s_mp[M];

  int b = blockIdx.x;
  int t = threadIdx.x;
  int g = t >> 5, lane = t & 31;

  // ---- stage indices / edge table / mp ids ----
  const int* wb = walks + b * (M * L * 3);
  #pragma unroll
  for (int i = 0; i < 6; ++i) ((int*)s_idx)[i * 256 + t] = wb[i * 256 + t];
  #pragma unroll
  for (int i = 0; i < 4; ++i) s_et[i * 256 + t] = edge_table[i * 256 + t];
  if (t < M) s_mp[t] = mp_type_idx[t];
  __syncthreads();

  // ---- phase 1: gather + fuse + mean.  group g -> m=g, lane -> float4 of E ----
  const float4* nt4 = (const float4*)node_table;   // row stride 32 float4
  float4 fb = ((const float4*)fc1_b)[lane];
  {
    float4 acc = make_float4(0.f, 0.f, 0.f, 0.f);
    for (int l0 = 0; l0 < L; l0 += 8) {
      float4 a[8], c[8];
      #pragma unroll
      for (int i = 0; i < 8; ++i) {
        int n1 = s_idx[g][l0 + i][0];
        int n2 = s_idx[g][l0 + i][1];
        a[i] = nt4[n1 * 32 + lane];
        c[i] = nt4[n2 * 32 + lane];
      }
      #pragma unroll
      for (int i = 0; i < 8; ++i) {
        int et = s_idx[g][l0 + i][2];
        float4 ev = ((const float4*)(s_et + et * E))[lane];
        acc.x += (a[i].x + fb.x) * (c[i].x + fb.x) * ev.x;
        acc.y += (a[i].y + fb.y) * (c[i].y + fb.y) * ev.y;
        acc.z += (a[i].z + fb.z) * (c[i].z + fb.z) * ev.z;
        acc.w += (a[i].w + fb.w) * (c[i].w + fb.w) * ev.w;
      }
    }
    const float inv = 1.0f / (float)L;
    acc.x *= inv; acc.y *= inv; acc.z *= inv; acc.w *= inv;
    ((float4*)s_x[g])[lane] = acc;
  }
  __syncthreads();

  // ---- phase 2: agg1 = agg0 @ W_mp[mp] + b_mp[mp].  lane -> 4 outputs ----
  {
    int mp = s_mp[g];
    const float4* W4 = (const float4*)(W_mp + mp * E * E);  // [e][o/4]
    float4 acc = make_float4(0.f, 0.f, 0.f, 0.f);
    for (int e = 0; e < E; ++e) {
      float x = s_x[g][e];                 // broadcast within group
      float4 w = W4[e * 32 + lane];
      acc.x += x * w.x; acc.y += x * w.y; acc.z += x * w.z; acc.w += x * w.w;
    }
    float4 bb = ((const float4*)(b_mp + mp * E))[lane];
    acc.x += bb.x; acc.y += bb.y; acc.z += bb.z; acc.w += bb.w;
    ((float4*)s_y[g])[lane] = acc;
  }
  __syncthreads();

  // ---- phase 3: qkv = agg1 @ WqkvT + bqkv (3 passes of 128 outputs) ----
  #pragma unroll
  for (int p = 0; p < 3; ++p) {
    float4 acc = make_float4(0.f, 0.f, 0.f, 0.f);
    for (int e = 0; e < E; ++e) {
      float x = s_y[g][e];                 // broadcast within group
      float4 w = ((const float4*)(WqkvT + e * E3))[p * 32 + lane];
      acc.x += x * w.x; acc.y += x * w.y; acc.z += x * w.z; acc.w += x * w.w;
    }
    float4 bb = ((const float4*)bqkv)[p * 32 + lane];
    int base = p * 128 + lane * 4;
    s_qkv[g][base + 0] = acc.x + bb.x;
    s_qkv[g][base + 1] = acc.y + bb.y;
    s_qkv[g][base + 2] = acc.z + bb.z;
    s_qkv[g][base + 3] = acc.w + bb.w;
  }
  __syncthreads();

  // ---- phase 4a: scores[h][m][n] = q.k / 4 ----
  #pragma unroll
  for (int i = 0; i < 2; ++i) {
    int idx = i * 256 + t;                 // 0..511
    int h = idx >> 6;
    int mq = (idx >> 3) & 7;
    int n = idx & 7;
    float s = 0.f;
    #pragma unroll
    for (int d = 0; d < HD; ++d)
      s += s_qkv[mq][h * HD + d] * s_qkv[n][E + h * HD + d];
    s_sc[h][mq][n] = s * 0.25f;
  }
  __syncthreads();

  // ---- phase 4b: softmax over n ----
  if (t < 64) {
    int h = t >> 3, mq = t & 7;
    float mx = -1e30f;
    #pragma unroll
    for (int n = 0; n < 8; ++n) mx = fmaxf(mx, s_sc[h][mq][n]);
    float ex[8];
    float sum = 0.f;
    #pragma unroll
    for (int n = 0; n < 8; ++n) { ex[n] = __expf(s_sc[h][mq][n] - mx); sum += ex[n]; }
    float inv = 1.0f / sum;
    #pragma unroll
    for (int n = 0; n < 8; ++n) s_sc[h][mq][n] = ex[n] * inv;
  }
  __syncthreads();

  // ---- phase 4c: o[m][col] = sum_n attn[h][m][n] * v[n][col] ----
  #pragma unroll
  for (int i = 0; i < 4; ++i) {
    int idx = i * 256 + t;                 // 0..1023
    int mq = idx >> 7;
    int col = idx & 127;
    int h = col >> 4;
    float s = 0.f;
    #pragma unroll
    for (int n = 0; n < 8; ++n)
      s += s_sc[h][mq][n] * s_qkv[n][2 * E + col];
    s_o[mq][col] = s;
  }
  __syncthreads();

  // ---- phase 5: out = o @ WoT + bo.  group g -> m=g, lane -> 4 outputs ----
  {
    const float4* Wo4 = (const float4*)WoT;
    float4 acc = make_float4(0.f, 0.f, 0.f, 0.f);
    for (int e = 0; e < E; ++e) {
      float x = s_o[g][e];                 // broadcast within group
      float4 w = Wo4[e * 32 + lane];
      acc.x += x * w.x; acc.y += x * w.y; acc.z += x * w.z; acc.w += x * w.w;
    }
    float4 bb = ((const float4*)bo)[lane];
    acc.x += bb.x; acc.y += bb.y; acc.z += bb.z; acc.w += bb.w;
    ((float4*)(out + (g * B + b) * E))[lane] = acc;
  }
}

// ---------------------------------------------------------------------------
extern "C" void kernel_launch(void* const* d_in, const int* in_sizes, int n_in,
                              void* d_out, int out_size, void* d_ws, size_t ws_size,
                              hipStream_t stream) {
  const int*   mp_type_idx = (const int*)d_in[1];
  const int*   walks       = (const int*)d_in[2];
  const float* node_table  = (const float*)d_in[3];
  const float* fc1_b       = (const float*)d_in[4];
  const float* edge_table  = (const float*)d_in[5];
  const float* W_mp        = (const float*)d_in[6];
  const float* b_mp        = (const float*)d_in[7];
  const float* Wqkv        = (const float*)d_in[8];
  const float* bqkv        = (const float*)d_in[9];
  const float* Wo          = (const float*)d_in[10];
  const float* bo          = (const float*)d_in[11];
  float* out = (float*)d_out;

  char* ws = (char*)d_ws;
  float* WqkvT = (float*)(ws);                    // 192 KB
  float* WoT   = (float*)(ws + (256 << 10));      // 64 KB

  k_transpose<<<dim3(256), dim3(256), 0, stream>>>(Wqkv, Wo, WqkvT, WoT);
  k_fused<<<dim3(B), dim3(256), 0, stream>>>(
      walks, node_table, fc1_b, edge_table, mp_type_idx,
      W_mp, b_mp, WqkvT, bqkv, WoT, bo, out);
}

// Round 4
// 189.768 us; speedup vs baseline: 1.1127x; 1.0734x over previous
//
#include <hip/hip_runtime.h>

#define B 256
#define M 8
#define L 64
#define E 128
#define H 8
#define HD 16
#define NET 8
#define E3 384

// ---------------------------------------------------------------------------
// K0: transpose Wqkv [384,128] -> WqkvT [128,384]; Wo [128,128] -> WoT [128,128]
// ---------------------------------------------------------------------------
__global__ __launch_bounds__(256) void k_transpose(
    const float* __restrict__ Wqkv, const float* __restrict__ Wo,
    float* __restrict__ WqkvT, float* __restrict__ WoT) {
  int idx = blockIdx.x * 256 + threadIdx.x;   // grid covers exactly 65536
  if (idx < E * E3) {
    int e = idx / E3;
    int o = idx - e * E3;
    WqkvT[idx] = Wqkv[o * E + e];
  } else {
    int j = idx - E * E3;                     // j < 16384
    int e = j >> 7, o = j & 127;
    WoT[j] = Wo[o * E + e];
  }
}

// ---------------------------------------------------------------------------
// K1 (fused, 1024 threads): one block per target node b; 16 waves/CU.
//   ph1: gather+fuse+mean   (32 groups = m x L-quarter, 16-deep load batch)
//   ph2: mp-linear          (1024 thr = (m,o) scalar, coalesced W)
//   ph3: qkv proj           (768 thr = (m-half, o), acc[4] over m: W read 2x)
//   ph4: attention M=8,H=8  (LDS)
//   ph5: out proj           (512 thr = (m-pair, o), acc[2] over m: W read 4x)
// ---------------------------------------------------------------------------
__global__ __launch_bounds__(1024) void k_fused(
    const int* __restrict__ walks, const float* __restrict__ node_table,
    const float* __restrict__ fc1_b, const float* __restrict__ edge_table,
    const int* __restrict__ mp_type_idx,
    const float* __restrict__ W_mp, const float* __restrict__ b_mp,
    const float* __restrict__ WqkvT, const float* __restrict__ bqkv,
    const float* __restrict__ WoT, const float* __restrict__ bo,
    float* __restrict__ out) {
  __shared__ int    s_idx[M][L][3];      // 6 KB
  __shared__ float  s_et[NET * E];       // 4 KB
  __shared__ float4 s_red[32][32];       // 16 KB gather partials
  __shared__ float  s_x[M][E];           // agg0
  __shared__ float  s_y[M][E];           // agg1
  __shared__ float  s_qkv[M][E3 + 1];    // 12 KB (+1: rows on distinct banks)
  __shared__ float  s_sc[H][M][M];
  __shared__ float  s_o[M][E];
  __shared__ int    s_mp[M];

  int b = blockIdx.x;
  int t = threadIdx.x;
  int g = t >> 5, lane = t & 31;

  // ---- stage walk indices / edge table / mp ids ----
  const int* wb = walks + b * (M * L * 3);
  for (int idx = t; idx < M * L * 3; idx += 1024) ((int*)s_idx)[idx] = wb[idx];
  s_et[t] = edge_table[t];               // NET*E == 1024
  if (t < M) s_mp[t] = mp_type_idx[t];
  __syncthreads();

  // ---- phase 1: gather + fuse + mean.  group g = (m, quarter q) ----
  {
    const float4* nt4 = (const float4*)node_table;   // row stride 32 float4
    float4 fb = ((const float4*)fc1_b)[lane];
    int m = g >> 2, q = g & 3;
    float4 acc = make_float4(0.f, 0.f, 0.f, 0.f);
    #pragma unroll
    for (int bi = 0; bi < 2; ++bi) {
      int l0 = q * 16 + bi * 8;
      float4 a[8], c[8];
      #pragma unroll
      for (int i = 0; i < 8; ++i) {
        int n1 = s_idx[m][l0 + i][0];
        int n2 = s_idx[m][l0 + i][1];
        a[i] = nt4[n1 * 32 + lane];
        c[i] = nt4[n2 * 32 + lane];
      }
      #pragma unroll
      for (int i = 0; i < 8; ++i) {
        int et = s_idx[m][l0 + i][2];
        float4 ev = ((const float4*)(s_et + et * E))[lane];
        acc.x += (a[i].x + fb.x) * (c[i].x + fb.x) * ev.x;
        acc.y += (a[i].y + fb.y) * (c[i].y + fb.y) * ev.y;
        acc.z += (a[i].z + fb.z) * (c[i].z + fb.z) * ev.z;
        acc.w += (a[i].w + fb.w) * (c[i].w + fb.w) * ev.w;
      }
    }
    s_red[g][lane] = acc;
  }
  __syncthreads();
  if (t < 256) {
    int m = t >> 5, ln = t & 31;
    float4 s = s_red[m * 4][ln];
    #pragma unroll
    for (int q = 1; q < 4; ++q) {
      float4 v = s_red[m * 4 + q][ln];
      s.x += v.x; s.y += v.y; s.z += v.z; s.w += v.w;
    }
    const float inv = 1.0f / (float)L;
    s.x *= inv; s.y *= inv; s.z *= inv; s.w *= inv;
    ((float4*)s_x[m])[ln] = s;
  }
  __syncthreads();

  // ---- phase 2: agg1 = agg0 @ W_mp[mp] + b_mp.  t = (m, o) scalar ----
  {
    int m = t >> 7, o = t & 127;
    int mp = s_mp[m];
    const float* W = W_mp + mp * E * E;
    float acc = 0.f;
    for (int e = 0; e < E; ++e)
      acc += s_x[m][e] * W[e * E + o];     // s_x broadcast; W coalesced
    s_y[m][o] = acc + b_mp[mp * E + o];
  }
  __syncthreads();

  // ---- phase 3: qkv = agg1 @ WqkvT + bqkv.  768 thr: (half, o), acc[4] ----
  if (t < 768) {
    int half = t / 384;          // wave-uniform (384 = 6 waves)
    int o = t - half * 384;
    float acc[4] = {0.f, 0.f, 0.f, 0.f};
    for (int e = 0; e < E; ++e) {
      float w = WqkvT[e * E3 + o];
      #pragma unroll
      for (int j = 0; j < 4; ++j) acc[j] += s_y[half * 4 + j][e] * w;
    }
    float bias = bqkv[o];
    #pragma unroll
    for (int j = 0; j < 4; ++j) s_qkv[half * 4 + j][o] = acc[j] + bias;
  }
  __syncthreads();

  // ---- phase 4a: scores[h][m][n] = q.k / sqrt(16) ----
  if (t < 512) {
    int h = t >> 6, mq = (t >> 3) & 7, n = t & 7;
    float s = 0.f;
    #pragma unroll
    for (int d = 0; d < HD; ++d)
      s += s_qkv[mq][h * HD + d] * s_qkv[n][E + h * HD + d];
    s_sc[h][mq][n] = s * 0.25f;
  }
  __syncthreads();

  // ---- phase 4b: softmax over n ----
  if (t < 64) {
    int h = t >> 3, mq = t & 7;
    float mx = -1e30f;
    #pragma unroll
    for (int n = 0; n < 8; ++n) mx = fmaxf(mx, s_sc[h][mq][n]);
    float ex[8];
    float sum = 0.f;
    #pragma unroll
    for (int n = 0; n < 8; ++n) { ex[n] = __expf(s_sc[h][mq][n] - mx); sum += ex[n]; }
    float inv = 1.0f / sum;
    #pragma unroll
    for (int n = 0; n < 8; ++n) s_sc[h][mq][n] = ex[n] * inv;
  }
  __syncthreads();

  // ---- phase 4c: o[m][col] = sum_n attn[h][m][n] * v[n][col] ----
  {
    int mq = t >> 7, col = t & 127, h = col >> 4;
    float s = 0.f;
    #pragma unroll
    for (int n = 0; n < 8; ++n)
      s += s_sc[h][mq][n] * s_qkv[n][2 * E + col];
    s_o[mq][col] = s;
  }
  __syncthreads();

  // ---- phase 5: out = o @ WoT + bo.  512 thr: (m-pair, o), acc[2] ----
  if (t < 512) {
    int pm = t >> 7, o = t & 127;
    float acc[2] = {0.f, 0.f};
    for (int e = 0; e < E; ++e) {
      float w = WoT[e * E + o];
      acc[0] += s_o[pm * 2][e] * w;
      acc[1] += s_o[pm * 2 + 1][e] * w;
    }
    float bias = bo[o];
    out[((pm * 2) * B + b) * E + o]     = acc[0] + bias;
    out[((pm * 2 + 1) * B + b) * E + o] = acc[1] + bias;
  }
}

// ---------------------------------------------------------------------------
extern "C" void kernel_launch(void* const* d_in, const int* in_sizes, int n_in,
                              void* d_out, int out_size, void* d_ws, size_t ws_size,
                              hipStream_t stream) {
  const int*   mp_type_idx = (const int*)d_in[1];
  const int*   walks       = (const int*)d_in[2];
  const float* node_table  = (const float*)d_in[3];
  const float* fc1_b       = (const float*)d_in[4];
  const float* edge_table  = (const float*)d_in[5];
  const float* W_mp        = (const float*)d_in[6];
  const float* b_mp        = (const float*)d_in[7];
  const float* Wqkv        = (const float*)d_in[8];
  const float* bqkv        = (const float*)d_in[9];
  const float* Wo          = (const float*)d_in[10];
  const float* bo          = (const float*)d_in[11];
  float* out = (float*)d_out;

  char* ws = (char*)d_ws;
  float* WqkvT = (float*)(ws);                    // 192 KB
  float* WoT   = (float*)(ws + (256 << 10));      // 64 KB

  k_transpose<<<dim3(256), dim3(256), 0, stream>>>(Wqkv, Wo, WqkvT, WoT);
  k_fused<<<dim3(B), dim3(1024), 0, stream>>>(
      walks, node_table, fc1_b, edge_table, mp_type_idx,
      W_mp, b_mp, WqkvT, bqkv, WoT, bo, out);
}